// Round 1
// baseline (300.476 us; speedup 1.0000x reference)
//
#include <hip/hip_runtime.h>
#include <hip/hip_bf16.h>

// GemmRS: out[m,n] = sum_{w,k} A[w,m,k]*B[w,n,k]
// A: [8,8192,512] f32, B: [8,1024,512] f32, out: [8192,1024] f32.
// Phase 1: convert A,B -> bf16 in d_ws (needs 72 MB; fallback below if not).
// Phase 2: bf16 MFMA GEMM, BM=128 BN=64 BK=64, grid 1024.
//   R1 changes: (a) double-buffered LDS, stage-next issued BEFORE compute,
//   ONE __syncthreads per K-step (T3 minimum-2-phase; barrier's vmcnt(0)
//   drain doubles as the prefetch fence); (b) bijective XCD swizzle of the
//   block id so each XCD owns 8 contiguous M-panel rows (T1; kills the
//   3.7x A-panel over-fetch); (c) s_setprio around the MFMA cluster (T5).

#define WS 8
#define MM 8192
#define KK 512
#define NN 1024
#define KTOT (WS * KK)  // 4096
#define BM 128
#define BN 64
#define BK 64
#define NBLK ((MM / BM) * (NN / BN))  // 1024, divisible by 8

#define A_ELEMS ((size_t)WS * MM * KK)  // 33,554,432
#define B_ELEMS ((size_t)WS * NN * KK)  //  4,194,304
#define WS_NEEDED ((A_ELEMS + B_ELEMS) * 2)  // 75,497,472 bytes

typedef __attribute__((ext_vector_type(8))) short short8;
typedef __attribute__((ext_vector_type(4))) short short4v;
typedef __attribute__((ext_vector_type(4))) float floatx4;

static __device__ inline short f2bf(float f) {
    union { __hip_bfloat16 h; short s; } u;
    u.h = __float2bfloat16(f);  // RNE
    return u.s;
}

static __device__ inline void glds16(const short* g, short* l) {
    __builtin_amdgcn_global_load_lds(
        (const __attribute__((address_space(1))) unsigned int*)(uintptr_t)g,
        (__attribute__((address_space(3))) unsigned int*)(uintptr_t)l,
        16, 0, 0);
}

// ---------------- Phase 1: f32 -> bf16 convert (streaming) ----------------
#define CVT_ABLOCKS 16384
#define CVT_NBLOCKS 18432

__global__ __launch_bounds__(256)
void cvt_f32_bf16(const float* __restrict__ A, const float* __restrict__ B,
                  short* __restrict__ Abf, short* __restrict__ Bbf) {
    const float* src;
    short* dst;
    size_t base;
    if (blockIdx.x < CVT_ABLOCKS) {
        src = A; dst = Abf;
        base = ((size_t)blockIdx.x * 256 + threadIdx.x) * 8;
    } else {
        src = B; dst = Bbf;
        base = ((size_t)(blockIdx.x - CVT_ABLOCKS) * 256 + threadIdx.x) * 8;
    }
    float4 v0 = *(const float4*)(src + base);
    float4 v1 = *(const float4*)(src + base + 4);
    short8 o = { f2bf(v0.x), f2bf(v0.y), f2bf(v0.z), f2bf(v0.w),
                 f2bf(v1.x), f2bf(v1.y), f2bf(v1.z), f2bf(v1.w) };
    *(short8*)(dst + base) = o;
}

// ---------------- Phase 2: bf16 GEMM (dbuf + XCD swizzle + setprio) -------
__global__ __launch_bounds__(256, 3)
void gemm_bf16_rs(const short* __restrict__ Abf, const short* __restrict__ Bbf,
                  float* __restrict__ C) {
    __shared__ short As[2][BM * BK];  // 32 KB
    __shared__ short Bs[2][BN * BK];  // 16 KB

    const int tid  = threadIdx.x;
    const int lane = tid & 63;
    const int wid  = tid >> 6;

    // T1: bijective XCD swizzle. Dispatch order is x-fastest, so linear id
    // lin -> XCD (lin & 7). Remap so XCD j owns contiguous tiles
    // [j*128, (j+1)*128) = 8 full M-panel rows (8 MB A + 8.4 MB B working
    // set per XCD instead of all 64 MB of A).
    const int lin = blockIdx.y * gridDim.x + blockIdx.x;       // 0..1023
    const int T   = (lin & 7) * (NBLK / 8) + (lin >> 3);       // bijective
    const int ty  = T >> 4;          // 0..63  (M tile)
    const int tx  = T & 15;          // 0..15  (N tile)
    const int m0  = ty * BM;
    const int n0  = tx * BN;

    const int wr = wid >> 1, wc = wid & 1;
    const int lm = lane & 15, quad = lane >> 4;

    // Staging geometry: chunk = 64 lanes x 16B = 8 rows x 8 segs (seg = 8 bf16).
    // Source seg is XOR-swizzled so stored position p of row r holds logical
    // seg p ^ (r&7)  (read side compensates identically).
    const int lrow = lane >> 3;
    const int ss   = (lane & 7) ^ lrow;

    size_t gA[4], gB[2];
#pragma unroll
    for (int t = 0; t < 4; ++t)
        gA[t] = (size_t)(m0 + wid * 32 + t * 8 + lrow) * KK + ss * 8;
#pragma unroll
    for (int t = 0; t < 2; ++t)
        gB[t] = (size_t)(n0 + wid * 16 + t * 8 + lrow) * KK + ss * 8;

    floatx4 acc[4][2];
#pragma unroll
    for (int i = 0; i < 4; ++i)
#pragma unroll
        for (int j = 0; j < 2; ++j) acc[i][j] = (floatx4)0.f;

    auto stage = [&](int buf, int kt) {
        const int w  = kt >> 9;         // rank bank (uniform)
        const int kk = kt & (KK - 1);   // offset inside bank (uniform)
        const short* Aw = Abf + (size_t)w * MM * KK + kk;
        const short* Bw = Bbf + (size_t)w * NN * KK + kk;
#pragma unroll
        for (int t = 0; t < 4; ++t)
            glds16(Aw + gA[t], &As[buf][(wid * 4 + t) * 512 + lane * 8]);
#pragma unroll
        for (int t = 0; t < 2; ++t)
            glds16(Bw + gB[t], &Bs[buf][(wid * 2 + t) * 512 + lane * 8]);
    };

    // Prologue: stage tile 0; the barrier's vmcnt(0) drain makes it ready.
    stage(0, 0);
    __syncthreads();

    for (int kt = 0; kt < KTOT; kt += BK) {
        const int cur = (kt >> 6) & 1;
        // Issue next tile's staging FIRST: its HBM/L2 latency hides under
        // the ds_read + MFMA below; the single end-of-iter barrier
        // (vmcnt(0) lgkmcnt(0) + s_barrier) is the only fence.
        if (kt + BK < KTOT) stage(cur ^ 1, kt + BK);

        short8 af[2][4], bfr[2][2];
#pragma unroll
        for (int kc = 0; kc < 2; ++kc) {
#pragma unroll
            for (int i = 0; i < 4; ++i) {
                const int row = wr * 64 + i * 16 + lm;
                const int sa  = (kc * 4 + quad) ^ (lm & 7);
                af[kc][i] = *(const short8*)&As[cur][row * BK + sa * 8];
            }
#pragma unroll
            for (int j = 0; j < 2; ++j) {
                const int row = wc * 32 + j * 16 + lm;
                const int sb  = (kc * 4 + quad) ^ (lm & 7);
                bfr[kc][j] = *(const short8*)&Bs[cur][row * BK + sb * 8];
            }
        }
        __builtin_amdgcn_s_setprio(1);
#pragma unroll
        for (int kc = 0; kc < 2; ++kc)
#pragma unroll
            for (int i = 0; i < 4; ++i)
#pragma unroll
                for (int j = 0; j < 2; ++j)
                    acc[i][j] = __builtin_amdgcn_mfma_f32_16x16x32_bf16(
                        af[kc][i], bfr[kc][j], acc[i][j], 0, 0, 0);
        __builtin_amdgcn_s_setprio(0);
        __syncthreads();  // drains vmcnt (next tile staged) + lgkm (reads done)
    }

    // Epilogue: C/D layout col = lane&15 (n), row = quad*4 + r (m) [m89]
#pragma unroll
    for (int i = 0; i < 4; ++i)
#pragma unroll
        for (int j = 0; j < 2; ++j) {
            const int n = n0 + wc * 32 + j * 16 + lm;
#pragma unroll
            for (int r = 0; r < 4; ++r) {
                const int m = m0 + wr * 64 + i * 16 + quad * 4 + r;
                C[(size_t)m * NN + n] = acc[i][j][r];
            }
        }
}

// ---------------- Fallback (round-1 fused kernel, ws too small) ----------------
__global__ __launch_bounds__(256, 2)
void gemm_rs_fused(const float* __restrict__ A, const float* __restrict__ B,
                   float* __restrict__ C) {
    __shared__ short As[128 * 32];
    __shared__ short Bs[128 * 32];
    const int tid = threadIdx.x;
    const int m0 = blockIdx.y * 128;
    const int n0 = blockIdx.x * 128;
    const int wid = tid >> 6, lane = tid & 63;
    const int wr = wid >> 1, wc = wid & 1;
    const int lm = lane & 15, quad = lane >> 4;
    floatx4 acc[4][4];
#pragma unroll
    for (int i = 0; i < 4; ++i)
#pragma unroll
        for (int j = 0; j < 4; ++j) acc[i][j] = (floatx4)0.f;
    for (int kt = 0; kt < KTOT; kt += 32) {
        const int w = kt >> 9, kk = kt & (KK - 1);
        const float* Aw = A + (size_t)w * MM * KK;
        const float* Bw = B + (size_t)w * NN * KK;
        __syncthreads();
#pragma unroll
        for (int i = 0; i < 4; ++i) {
            const int idx = i * 256 + tid;
            const int row = idx >> 3;
            const int c4 = (idx & 7) * 4;
            float4 av = *(const float4*)&Aw[(size_t)(m0 + row) * KK + kk + c4];
            float4 bv = *(const float4*)&Bw[(size_t)(n0 + row) * KK + kk + c4];
            short4v a4 = { f2bf(av.x), f2bf(av.y), f2bf(av.z), f2bf(av.w) };
            short4v b4 = { f2bf(bv.x), f2bf(bv.y), f2bf(bv.z), f2bf(bv.w) };
            *(short4v*)&As[row * 32 + c4] = a4;
            *(short4v*)&Bs[row * 32 + c4] = b4;
        }
        __syncthreads();
        short8 af[4], bfr[4];
#pragma unroll
        for (int i = 0; i < 4; ++i)
            af[i] = *(const short8*)&As[(wr * 64 + i * 16 + lm) * 32 + quad * 8];
#pragma unroll
        for (int j = 0; j < 4; ++j)
            bfr[j] = *(const short8*)&Bs[(wc * 64 + j * 16 + lm) * 32 + quad * 8];
#pragma unroll
        for (int i = 0; i < 4; ++i)
#pragma unroll
            for (int j = 0; j < 4; ++j)
                acc[i][j] = __builtin_amdgcn_mfma_f32_16x16x32_bf16(
                    af[i], bfr[j], acc[i][j], 0, 0, 0);
    }
#pragma unroll
    for (int i = 0; i < 4; ++i)
#pragma unroll
        for (int j = 0; j < 4; ++j) {
            const int n = n0 + wc * 64 + j * 16 + lm;
#pragma unroll
            for (int r = 0; r < 4; ++r) {
                const int m = m0 + wr * 64 + i * 16 + quad * 4 + r;
                C[(size_t)m * NN + n] = acc[i][j][r];
            }
        }
}

extern "C" void kernel_launch(void* const* d_in, const int* in_sizes, int n_in,
                              void* d_out, int out_size, void* d_ws, size_t ws_size,
                              hipStream_t stream) {
    const float* A = (const float*)d_in[0];  // [8,8192,512]
    const float* B = (const float*)d_in[1];  // [8,1024,512]
    float* C = (float*)d_out;                // [8192,1024]

    if (ws_size >= WS_NEEDED) {
        short* Abf = (short*)d_ws;
        short* Bbf = Abf + A_ELEMS;
        cvt_f32_bf16<<<CVT_NBLOCKS, 256, 0, stream>>>(A, B, Abf, Bbf);
        dim3 grid(NN / BN, MM / BM);  // (16, 64) = 1024 blocks
        gemm_bf16_rs<<<grid, 256, 0, stream>>>(Abf, Bbf, C);
    } else {
        dim3 grid(NN / 128, MM / 128);  // (8, 64)
        gemm_rs_fused<<<grid, 256, 0, stream>>>(A, B, C);
    }
}

// Round 2
// 271.191 us; speedup vs baseline: 1.1080x; 1.1080x over previous
//
#include <hip/hip_runtime.h>
#include <hip/hip_bf16.h>

// GemmRS: out[m,n] = sum_{w,k} A[w,m,k]*B[w,n,k]
// A: [8,8192,512] f32, B: [8,1024,512] f32, out: [8192,1024] f32.
// Phase 1: convert A,B -> bf16 in d_ws (needs 72 MB; fallback below if not).
// Phase 2: bf16 MFMA GEMM.
//   R1: dbuf LDS (1 barrier/K-step), bijective XCD swizzle, setprio.
//       Result: FETCH 276->108 MB, but staging-throughput bound at 42.7 FLOP/B.
//   R2: BN 64->128 (tile 128x128, 4x4 frags/wave, 32 MFMA/wave/step).
//       FLOP/B 42.7->64, staged bytes 1.61->1.07 GB. Sync structure UNCHANGED.

#define WS 8
#define MM 8192
#define KK 512
#define NN 1024
#define KTOT (WS * KK)  // 4096
#define BM 128
#define BN 128
#define BK 64
#define NBLK ((MM / BM) * (NN / BN))  // 512, divisible by 8

#define A_ELEMS ((size_t)WS * MM * KK)  // 33,554,432
#define B_ELEMS ((size_t)WS * NN * KK)  //  4,194,304
#define WS_NEEDED ((A_ELEMS + B_ELEMS) * 2)  // 75,497,472 bytes

typedef __attribute__((ext_vector_type(8))) short short8;
typedef __attribute__((ext_vector_type(4))) short short4v;
typedef __attribute__((ext_vector_type(4))) float floatx4;

static __device__ inline short f2bf(float f) {
    union { __hip_bfloat16 h; short s; } u;
    u.h = __float2bfloat16(f);  // RNE
    return u.s;
}

static __device__ inline void glds16(const short* g, short* l) {
    __builtin_amdgcn_global_load_lds(
        (const __attribute__((address_space(1))) unsigned int*)(uintptr_t)g,
        (__attribute__((address_space(3))) unsigned int*)(uintptr_t)l,
        16, 0, 0);
}

// ---------------- Phase 1: f32 -> bf16 convert (streaming) ----------------
#define CVT_ABLOCKS 16384
#define CVT_NBLOCKS 18432

__global__ __launch_bounds__(256)
void cvt_f32_bf16(const float* __restrict__ A, const float* __restrict__ B,
                  short* __restrict__ Abf, short* __restrict__ Bbf) {
    const float* src;
    short* dst;
    size_t base;
    if (blockIdx.x < CVT_ABLOCKS) {
        src = A; dst = Abf;
        base = ((size_t)blockIdx.x * 256 + threadIdx.x) * 8;
    } else {
        src = B; dst = Bbf;
        base = ((size_t)(blockIdx.x - CVT_ABLOCKS) * 256 + threadIdx.x) * 8;
    }
    float4 v0 = *(const float4*)(src + base);
    float4 v1 = *(const float4*)(src + base + 4);
    short8 o = { f2bf(v0.x), f2bf(v0.y), f2bf(v0.z), f2bf(v0.w),
                 f2bf(v1.x), f2bf(v1.y), f2bf(v1.z), f2bf(v1.w) };
    *(short8*)(dst + base) = o;
}

// ---------------- Phase 2: bf16 GEMM 128x128 (dbuf + XCD swizzle) ---------
// 4 waves: wr in {0,1} (64 rows each), wc in {0,1} (64 cols each).
// Per wave: 4 m-frags x 4 n-frags x (BK/32=2) -> 32 MFMA/iter.
__global__ __launch_bounds__(256, 2)
void gemm_bf16_rs(const short* __restrict__ Abf, const short* __restrict__ Bbf,
                  float* __restrict__ C) {
    __shared__ short As[2][BM * BK];  // 32 KB
    __shared__ short Bs[2][BN * BK];  // 32 KB

    const int tid  = threadIdx.x;
    const int lane = tid & 63;
    const int wid  = tid >> 6;

    // T1: bijective XCD swizzle. Linear id lin -> XCD (lin & 7). Remap so
    // XCD j owns contiguous tiles [j*64,(j+1)*64) = 8 contiguous M-panel
    // rows (8 MB A-panel + 8.4 MB B working set per XCD).
    const int lin = blockIdx.y * gridDim.x + blockIdx.x;       // 0..511
    const int T   = (lin & 7) * (NBLK / 8) + (lin >> 3);       // bijective
    const int ty  = T >> 3;          // 0..63  (M tile)
    const int tx  = T & 7;           // 0..7   (N tile)
    const int m0  = ty * BM;
    const int n0  = tx * BN;

    const int wr = wid >> 1, wc = wid & 1;
    const int lm = lane & 15, quad = lane >> 4;

    // Staging geometry: chunk = 64 lanes x 16B = 8 rows x 8 segs (seg = 8 bf16).
    // Source seg XOR-swizzled: stored position p of row r holds logical seg
    // p ^ (r&7); read side compensates identically.
    const int lrow = lane >> 3;
    const int ss   = (lane & 7) ^ lrow;

    size_t gA[4], gB[4];
#pragma unroll
    for (int t = 0; t < 4; ++t) {
        gA[t] = (size_t)(m0 + wid * 32 + t * 8 + lrow) * KK + ss * 8;
        gB[t] = (size_t)(n0 + wid * 32 + t * 8 + lrow) * KK + ss * 8;
    }

    floatx4 acc[4][4];
#pragma unroll
    for (int i = 0; i < 4; ++i)
#pragma unroll
        for (int j = 0; j < 4; ++j) acc[i][j] = (floatx4)0.f;

    auto stage = [&](int buf, int kt) {
        const int w  = kt >> 9;         // rank bank (uniform)
        const int kk = kt & (KK - 1);   // offset inside bank (uniform)
        const short* Aw = Abf + (size_t)w * MM * KK + kk;
        const short* Bw = Bbf + (size_t)w * NN * KK + kk;
#pragma unroll
        for (int t = 0; t < 4; ++t)
            glds16(Aw + gA[t], &As[buf][(wid * 4 + t) * 512 + lane * 8]);
#pragma unroll
        for (int t = 0; t < 4; ++t)
            glds16(Bw + gB[t], &Bs[buf][(wid * 4 + t) * 512 + lane * 8]);
    };

    // Prologue: stage tile 0; the barrier's vmcnt(0) drain makes it ready.
    stage(0, 0);
    __syncthreads();

    for (int kt = 0; kt < KTOT; kt += BK) {
        const int cur = (kt >> 6) & 1;
        // Issue next tile's staging FIRST: its HBM/L2 latency hides under
        // the ds_read + MFMA below; the single end-of-iter barrier
        // (vmcnt(0) lgkmcnt(0) + s_barrier) is the only fence.
        if (kt + BK < KTOT) stage(cur ^ 1, kt + BK);

        short8 af[2][4], bfr[2][4];
#pragma unroll
        for (int kc = 0; kc < 2; ++kc) {
#pragma unroll
            for (int i = 0; i < 4; ++i) {
                const int row = wr * 64 + i * 16 + lm;
                const int sa  = (kc * 4 + quad) ^ (lm & 7);
                af[kc][i] = *(const short8*)&As[cur][row * BK + sa * 8];
            }
#pragma unroll
            for (int j = 0; j < 4; ++j) {
                const int row = wc * 64 + j * 16 + lm;
                const int sb  = (kc * 4 + quad) ^ (lm & 7);
                bfr[kc][j] = *(const short8*)&Bs[cur][row * BK + sb * 8];
            }
        }
        __builtin_amdgcn_s_setprio(1);
#pragma unroll
        for (int kc = 0; kc < 2; ++kc)
#pragma unroll
            for (int i = 0; i < 4; ++i)
#pragma unroll
                for (int j = 0; j < 4; ++j)
                    acc[i][j] = __builtin_amdgcn_mfma_f32_16x16x32_bf16(
                        af[kc][i], bfr[kc][j], acc[i][j], 0, 0, 0);
        __builtin_amdgcn_s_setprio(0);
        __syncthreads();  // drains vmcnt (next tile staged) + lgkm (reads done)
    }

    // Epilogue: C/D layout col = lane&15 (n), row = quad*4 + r (m) [m89]
#pragma unroll
    for (int i = 0; i < 4; ++i)
#pragma unroll
        for (int j = 0; j < 4; ++j) {
            const int n = n0 + wc * 64 + j * 16 + lm;
#pragma unroll
            for (int r = 0; r < 4; ++r) {
                const int m = m0 + wr * 64 + i * 16 + quad * 4 + r;
                C[(size_t)m * NN + n] = acc[i][j][r];
            }
        }
}

// ---------------- Fallback (round-1 fused kernel, ws too small) ----------------
__global__ __launch_bounds__(256, 2)
void gemm_rs_fused(const float* __restrict__ A, const float* __restrict__ B,
                   float* __restrict__ C) {
    __shared__ short As[128 * 32];
    __shared__ short Bs[128 * 32];
    const int tid = threadIdx.x;
    const int m0 = blockIdx.y * 128;
    const int n0 = blockIdx.x * 128;
    const int wid = tid >> 6, lane = tid & 63;
    const int wr = wid >> 1, wc = wid & 1;
    const int lm = lane & 15, quad = lane >> 4;
    floatx4 acc[4][4];
#pragma unroll
    for (int i = 0; i < 4; ++i)
#pragma unroll
        for (int j = 0; j < 4; ++j) acc[i][j] = (floatx4)0.f;
    for (int kt = 0; kt < KTOT; kt += 32) {
        const int w = kt >> 9, kk = kt & (KK - 1);
        const float* Aw = A + (size_t)w * MM * KK;
        const float* Bw = B + (size_t)w * NN * KK;
        __syncthreads();
#pragma unroll
        for (int i = 0; i < 4; ++i) {
            const int idx = i * 256 + tid;
            const int row = idx >> 3;
            const int c4 = (idx & 7) * 4;
            float4 av = *(const float4*)&Aw[(size_t)(m0 + row) * KK + kk + c4];
            float4 bv = *(const float4*)&Bw[(size_t)(n0 + row) * KK + kk + c4];
            short4v a4 = { f2bf(av.x), f2bf(av.y), f2bf(av.z), f2bf(av.w) };
            short4v b4 = { f2bf(bv.x), f2bf(bv.y), f2bf(bv.z), f2bf(bv.w) };
            *(short4v*)&As[row * 32 + c4] = a4;
            *(short4v*)&Bs[row * 32 + c4] = b4;
        }
        __syncthreads();
        short8 af[4], bfr[4];
#pragma unroll
        for (int i = 0; i < 4; ++i)
            af[i] = *(const short8*)&As[(wr * 64 + i * 16 + lm) * 32 + quad * 8];
#pragma unroll
        for (int j = 0; j < 4; ++j)
            bfr[j] = *(const short8*)&Bs[(wc * 64 + j * 16 + lm) * 32 + quad * 8];
#pragma unroll
        for (int i = 0; i < 4; ++i)
#pragma unroll
            for (int j = 0; j < 4; ++j)
                acc[i][j] = __builtin_amdgcn_mfma_f32_16x16x32_bf16(
                    af[i], bfr[j], acc[i][j], 0, 0, 0);
    }
#pragma unroll
    for (int i = 0; i < 4; ++i)
#pragma unroll
        for (int j = 0; j < 4; ++j) {
            const int n = n0 + wc * 64 + j * 16 + lm;
#pragma unroll
            for (int r = 0; r < 4; ++r) {
                const int m = m0 + wr * 64 + i * 16 + quad * 4 + r;
                C[(size_t)m * NN + n] = acc[i][j][r];
            }
        }
}

extern "C" void kernel_launch(void* const* d_in, const int* in_sizes, int n_in,
                              void* d_out, int out_size, void* d_ws, size_t ws_size,
                              hipStream_t stream) {
    const float* A = (const float*)d_in[0];  // [8,8192,512]
    const float* B = (const float*)d_in[1];  // [8,1024,512]
    float* C = (float*)d_out;                // [8192,1024]

    if (ws_size >= WS_NEEDED) {
        short* Abf = (short*)d_ws;
        short* Bbf = Abf + A_ELEMS;
        cvt_f32_bf16<<<CVT_NBLOCKS, 256, 0, stream>>>(A, B, Abf, Bbf);
        dim3 grid(NN / BN, MM / BM);  // (8, 64) = 512 blocks
        gemm_bf16_rs<<<grid, 256, 0, stream>>>(Abf, Bbf, C);
    } else {
        dim3 grid(NN / 128, MM / 128);  // (8, 64)
        gemm_rs_fused<<<grid, 256, 0, stream>>>(A, B, C);
    }
}